// Round 6
// baseline (130.165 us; speedup 1.0000x reference)
//
#include <hip/hip_runtime.h>
#include <math.h>

// EnhancedFinancialGAT — analytical collapse (Round 0 proof: all N=2000 node
// rows identical + per-dst softmax sums to 1 (self-loop guarantees denom>=1)
// => each GAT layer is a dense 256->256 relu; edges/attention irrelevant).
//
// Round 12: fix MLP. v11 (global->VGPR->FMA streaming) reached ~29us kernel
// but its CH=4 chunked loop keeps only ~4 float4 in flight per thread; the
// per-CU L2 weight pull (1.47MB at ~60B/cyc, m56) needs 10-25KB outstanding
// to hit its ~10us floor. Restructure: 16 lanes/row x 4 float4, FOUR
// independent fully-unrolled sub-steps per layer (64 rows x 16 lanes = 1024
// threads each). No persistent fragments (v7's sin), no chunk serialization
// (v11's sin): sub-steps share nothing, so the scheduler issues sub-step
// j+1's loads during sub-step j's FMA+reduce — up to 16 float4/thread in
// flight, bounded live regs. fp32 end-to-end; 8 barriers total.

#define B_ITEMS 64

// Dot of one row slice: NF4 float4 per lane, G lanes per row.
// Returns the row dot-product reduced across the G lanes (valid in c==0).
template <int NF4, int G>
__device__ __forceinline__ float dotrow(const float* __restrict__ Wrow,
                                        const float* __restrict__ vin,  // LDS
                                        int c) {
    const float4* __restrict__ W4 = reinterpret_cast<const float4*>(Wrow);
    const float4* __restrict__ A4 = reinterpret_cast<const float4*>(vin);
    float acc = 0.f;
#pragma unroll
    for (int j = 0; j < NF4; ++j) {
        const int idx = j * G + c;
        float4 w = W4[idx];
        float4 a = A4[idx];
        acc = fmaf(w.x, a.x, acc);
        acc = fmaf(w.y, a.y, acc);
        acc = fmaf(w.z, a.z, acc);
        acc = fmaf(w.w, a.w, acc);
    }
#pragma unroll
    for (int s = 1; s < G; s <<= 1) acc += __shfl_xor(acc, s, 64);
    return acc;
}

// Uniform layer: M = NS*64 output rows, K = NF4*64 inputs, 16 lanes/row.
// All NS sub-steps unrolled & independent -> deep load pipelining.
template <int NF4, int NS>
__device__ __forceinline__ void layer16(const float* __restrict__ W,    // [M][K]
                                        const float* __restrict__ bias, // [M] global
                                        const float* __restrict__ vin,  // LDS [K]
                                        float* __restrict__ vout,       // LDS [M]
                                        int t) {
    const int c = t & 15;
    const int o0 = t >> 4;               // 0..63
    constexpr int K = NF4 * 64;
#pragma unroll
    for (int s = 0; s < NS; ++s) {
        const int o = s * 64 + o0;
        const float acc = dotrow<NF4, 16>(W + (size_t)o * K, vin, c);
        if (c == 0) vout[o] = fmaxf(acc + bias[o], 0.f);
    }
}

extern "C" __global__ __launch_bounds__(1024) void fin_gat_v12(
    const float* __restrict__ x,        // [64,64]
    const int* __restrict__ cidx,       // [64]
    const float* __restrict__ W_in,     // [256,64]
    const float* __restrict__ b_in,
    const float* __restrict__ gat_W,    // [3,256,256]
    const float* __restrict__ gat_b,    // [3,256]
    const float* __restrict__ emb,      // [2000,64]
    const float* __restrict__ W_fuse,   // [256,320]
    const float* __restrict__ b_fuse,
    const float* __restrict__ W_p1,     // [128,256]
    const float* __restrict__ b_p1,
    const float* __restrict__ W_p2,     // [64,128]
    const float* __restrict__ b_p2,
    const float* __restrict__ W_p3, const float* __restrict__ b_p3,
    const float* __restrict__ W_d1,     // [128,256]
    const float* __restrict__ b_d1,
    const float* __restrict__ W_d2,     // [64,128]
    const float* __restrict__ b_d2,
    const float* __restrict__ W_d3, const float* __restrict__ b_d3,
    float* __restrict__ out)            // [128]
{
    __shared__ float vecA[320];   // activations; emb parked at [256:320]
    __shared__ float vecB[256];
    __shared__ float xvec[64];

    const int b = blockIdx.x;
    const int t = threadIdx.x;
    const int c = t & 15;
    const int o0 = t >> 4;

    // ---- prologue: x, emb, head-dot weights (all independent loads) ----
    if (t < 64) {
        const int ci = cidx[b];
        xvec[t] = x[b * 64 + t];
        vecA[256 + t] = emb[(size_t)ci * 64 + t];
    }
    float wdot = 0.f, bdot = 0.f;
    if (t < 64)            wdot = W_p3[t];
    else if (t < 128)      wdot = W_d3[t - 64];
    if (t == 0)            bdot = b_p3[0];
    else if (t == 64)      bdot = b_d3[0];
    __syncthreads();

    // ---- L0: relu(W_in x): xvec -> vecB[0:256]  (K=64, NF4=1, NS=4) ----
    layer16<1, 4>(W_in, b_in, xvec, vecB, t);
    __syncthreads();

    // ---- GAT0: vecB -> vecA[0:256]  (K=256, NF4=4, NS=4) ----
    layer16<4, 4>(gat_W, gat_b, vecB, vecA, t);
    __syncthreads();

    // ---- GAT1: vecA -> vecB ----
    layer16<4, 4>(gat_W + 65536, gat_b + 256, vecA, vecB, t);
    __syncthreads();

    // ---- GAT2: vecB -> vecA[0:256] ----
    layer16<4, 4>(gat_W + 131072, gat_b + 512, vecB, vecA, t);
    __syncthreads();

    // ---- FUSE: vecA[0:320] (gat out ++ emb) -> vecB  (K=320, NF4=5) ----
    layer16<5, 4>(W_fuse, b_fuse, vecA, vecB, t);
    __syncthreads();

    // ---- P1 ++ D1: vecB -> vecA[0:256]  (two 128-row halves) ----
    {
#pragma unroll
        for (int s = 0; s < 4; ++s) {
            const int o = s * 64 + o0;                 // 0..255
            const float* Wr = (s < 2) ? (W_p1 + (size_t)o * 256)
                                      : (W_d1 + (size_t)(o - 128) * 256);
            const float bv = (s < 2) ? b_p1[o] : b_d1[o - 128];
            const float acc = dotrow<4, 16>(Wr, vecB, c);
            if (c == 0) vecA[o] = fmaxf(acc + bv, 0.f);
        }
    }
    __syncthreads();

    // ---- P2 ++ D2: vecA -> vecB[0:128]  (K=128, NF4=2, 2 sub-steps) ----
    {
#pragma unroll
        for (int s = 0; s < 2; ++s) {
            const int o = s * 64 + o0;                 // 0..127
            const float* Wr = (s == 0) ? (W_p2 + (size_t)o0 * 128)
                                       : (W_d2 + (size_t)o0 * 128);
            const float bv = (s == 0) ? b_p2[o0] : b_d2[o0];
            const float* vi = vecA + ((s == 0) ? 0 : 128);
            const float acc = dotrow<2, 16>(Wr, vi, c);
            if (c == 0) vecB[o] = fmaxf(acc + bv, 0.f);
        }
    }
    __syncthreads();

    // ---- final dots: wave 0 -> price, wave 1 -> direction ----
    if (t < 64) {
        float v = wdot * vecB[t];
#pragma unroll
        for (int off = 32; off > 0; off >>= 1) v += __shfl_down(v, off, 64);
        if (t == 0) out[b] = v + bdot;
    } else if (t < 128) {
        const int u = t - 64;
        float v = wdot * vecB[64 + u];
#pragma unroll
        for (int off = 32; off > 0; off >>= 1) v += __shfl_down(v, off, 64);
        if (u == 0) {
            float z = v + bdot;
            out[B_ITEMS + b] = 1.0f / (1.0f + expf(-z));
        }
    }
}

extern "C" void kernel_launch(void* const* d_in, const int* in_sizes, int n_in,
                              void* d_out, int out_size, void* d_ws, size_t ws_size,
                              hipStream_t stream) {
    const float* x      = (const float*)d_in[0];
    const int*   cidx   = (const int*)  d_in[1];
    // d_in[2]=edge_index, d_in[3]=edge_attr -> numerically irrelevant
    const float* W_in   = (const float*)d_in[4];
    const float* b_in   = (const float*)d_in[5];
    const float* gat_W  = (const float*)d_in[6];
    // d_in[7..10] = att params -> irrelevant
    const float* gat_b  = (const float*)d_in[11];
    const float* emb    = (const float*)d_in[12];
    const float* W_fuse = (const float*)d_in[13];
    const float* b_fuse = (const float*)d_in[14];
    const float* W_p1   = (const float*)d_in[15];
    const float* b_p1   = (const float*)d_in[16];
    const float* W_p2   = (const float*)d_in[17];
    const float* b_p2   = (const float*)d_in[18];
    const float* W_p3   = (const float*)d_in[19];
    const float* b_p3   = (const float*)d_in[20];
    const float* W_d1   = (const float*)d_in[21];
    const float* b_d1   = (const float*)d_in[22];
    const float* W_d2   = (const float*)d_in[23];
    const float* b_d2   = (const float*)d_in[24];
    const float* W_d3   = (const float*)d_in[25];
    const float* b_d3   = (const float*)d_in[26];

    (void)d_ws; (void)ws_size;   // unused: weights stream global->VGPR->FMA

    fin_gat_v12<<<B_ITEMS, 1024, 0, stream>>>(
        x, cidx, W_in, b_in, gat_W, gat_b, emb, W_fuse, b_fuse,
        W_p1, b_p1, W_p2, b_p2, W_p3, b_p3,
        W_d1, b_d1, W_d2, b_d2, W_d3, b_d3,
        (float*)d_out);
}